// Round 14
// baseline (353.598 us; speedup 1.0000x reference)
//
#include <hip/hip_runtime.h>
#include <hip/hip_bf16.h>
#include <hip/hip_fp16.h>

#define N_NODES 10000
#define N_EDGES 160000
#define FEAT_W 320
#define CHUNK 32

typedef _Float16 half8 __attribute__((ext_vector_type(8)));
typedef float f32x4 __attribute__((ext_vector_type(4)));

// fast gelu: tanh(y) = 1 - 2/(exp(2y)+1)  (no NaN at +/-inf, ~1e-7 abs err)
__device__ __forceinline__ float gelu_tanh(float x) {
    float x3 = x * x * x;
    float y = 0.7978845608028654f * (x + 0.044715f * x3);
    float th = 1.f - 2.f / (__expf(2.f * y) + 1.f);
    return 0.5f * x * (1.f + th);
}

// ---------------- prep: node transforms ∥ degree count+rank ∥ weight pack ---
// (R6/R7/R9/R12-verified)
__global__ __launch_bounds__(320) void prep_kernel(
    const float* __restrict__ node_input,
    const float* __restrict__ Wa0, const float* __restrict__ Wa1,
    const float* __restrict__ Wb0, const float* __restrict__ Wb1,
    float* __restrict__ feat_tbl, float* __restrict__ self_tbl,
    const int* __restrict__ edge_dst, int* __restrict__ counts,
    int* __restrict__ rank,
    const float* __restrict__ Wtp0, const float* __restrict__ Wtp1,
    const float* __restrict__ Wtp2, const float* __restrict__ Wtp3,
    const float* __restrict__ Wo0,  const float* __restrict__ Wo1,
    __half* __restrict__ wtp_pack, __half* __restrict__ wo_pack)
{
    __shared__ __align__(16) float xT[FEAT_W][8];   // 10.24 KB (NT branch only)
    const int t = threadIdx.x;

    if (blockIdx.x < 1250) {
        const int node0 = blockIdx.x * 8;
        for (int q = t; q < 640; q += 320) {            // 8 rows x 80 float4
            const int n = q / 80, c4 = q - n * 80;
            const float4 v = ((const float4*)(node_input + (size_t)(node0 + n) * FEAT_W))[c4];
            xT[c4 * 4 + 0][n] = v.x; xT[c4 * 4 + 1][n] = v.y;
            xT[c4 * 4 + 2][n] = v.z; xT[c4 * 4 + 3][n] = v.w;
        }
        __syncthreads();

        float accf[8] = {0,0,0,0,0,0,0,0}, accs[8] = {0,0,0,0,0,0,0,0};
        float scale;
        if (t < 128) {
            for (int v = 0; v < 128; ++v) {
                const float wa = Wa0[v * 128 + t];
                const float wb = Wb0[v * 128 + t];
                const float4 xa = *(const float4*)&xT[v][0];
                const float4 xb = *(const float4*)&xT[v][4];
                accf[0] += xa.x * wa; accf[1] += xa.y * wa; accf[2] += xa.z * wa; accf[3] += xa.w * wa;
                accf[4] += xb.x * wa; accf[5] += xb.y * wa; accf[6] += xb.z * wa; accf[7] += xb.w * wa;
                accs[0] += xa.x * wb; accs[1] += xa.y * wb; accs[2] += xa.z * wb; accs[3] += xa.w * wb;
                accs[4] += xb.x * wb; accs[5] += xb.y * wb; accs[6] += xb.z * wb; accs[7] += xb.w * wb;
            }
            scale = 0.08838834764831845f;               // 1/sqrt(128)
        } else {
            const int r = t - 128, u = r / 3, i = r - 3 * u;
            for (int v = 0; v < 64; ++v) {
                const float wa = Wa1[v * 64 + u];
                const float wb = Wb1[v * 64 + u];
                const int row = 128 + v * 3 + i;
                const float4 xa = *(const float4*)&xT[row][0];
                const float4 xb = *(const float4*)&xT[row][4];
                accf[0] += xa.x * wa; accf[1] += xa.y * wa; accf[2] += xa.z * wa; accf[3] += xa.w * wa;
                accf[4] += xb.x * wa; accf[5] += xb.y * wa; accf[6] += xb.z * wa; accf[7] += xb.w * wa;
                accs[0] += xa.x * wb; accs[1] += xa.y * wb; accs[2] += xa.z * wb; accs[3] += xa.w * wb;
                accs[4] += xb.x * wb; accs[5] += xb.y * wb; accs[6] += xb.z * wb; accs[7] += xb.w * wb;
            }
            scale = 0.125f;                             // 1/sqrt(64)
        }
#pragma unroll
        for (int n = 0; n < 8; ++n) {
            feat_tbl[(size_t)(node0 + n) * FEAT_W + t] = accf[n] * scale;
            self_tbl[(size_t)(node0 + n) * FEAT_W + t] = accs[n] * scale;
        }
    } else if (blockIdx.x < 1750) {
        const int e = (blockIdx.x - 1250) * 320 + t;    // 500*320 == N_EDGES
        rank[e] = atomicAdd(&counts[edge_dst[e]], 1);
    } else {
        const int gid = (blockIdx.x - 1750) * 320 + t;  // 120*320 = 38400
        if (gid < 1536) {                               // 24 tiles * 64 lanes
            const int lane = gid & 63;
            const int tile = gid >> 6;
            const int quad = lane >> 4, n16 = lane & 15;
            const int col = tile * 16 + n16;
            const float* src; int stride;
            if (col < 128)      { src = Wtp0 + col;         stride = 128; }
            else if (col < 256) { src = Wtp1 + (col - 128); stride = 128; }
            else if (col < 320) { src = Wtp2 + (col - 256); stride = 64;  }
            else                { src = Wtp3 + (col - 320); stride = 64;  }
            __half* dst = wtp_pack + (size_t)gid * 16;
#pragma unroll
            for (int s = 0; s < 2; ++s)
#pragma unroll
                for (int j = 0; j < 8; ++j)
                    dst[s * 8 + j] = (__half)src[(s * 32 + quad * 8 + j) * stride];
        } else if (gid < 38400) {
            const int i = gid - 1536;                   // 36864 = 192*128 + 192*64
            if (i < 24576) wo_pack[i] = (__half)Wo0[i];
            else           wo_pack[i] = (__half)Wo1[i - 24576];
        }
    }
}

// ---------------- CSR scan --------------------------------------------------
__global__ __launch_bounds__(1024) void scan_kernel(
    const int* __restrict__ counts, int* __restrict__ offsets)
{
    __shared__ int wsum[16];
    const int wid = threadIdx.x >> 6, lane = threadIdx.x & 63;
    int base = 0;
    for (int c = 0; c < 10; ++c) {            // 10*1024 >= 10000
        const int i = c * 1024 + threadIdx.x;
        const int v = (i < N_NODES) ? counts[i] : 0;
        int x = v;
#pragma unroll
        for (int off = 1; off < 64; off <<= 1) {
            int y = __shfl_up(x, off, 64);
            if (lane >= off) x += y;
        }
        if (lane == 63) wsum[wid] = x;
        __syncthreads();
        if (threadIdx.x < 16) {
            int s = wsum[threadIdx.x];
#pragma unroll
            for (int off = 1; off < 16; off <<= 1) {
                int y = __shfl_up(s, off, 64);
                if ((int)threadIdx.x >= off) s += y;
            }
            wsum[threadIdx.x] = s;
        }
        __syncthreads();
        const int waveoff = (wid == 0) ? 0 : wsum[wid - 1];
        const int excl = base + waveoff + x - v;
        if (i < N_NODES) offsets[i] = excl;
        const int tot = wsum[15];
        __syncthreads();
        base += tot;
    }
    if (threadIdx.x == 0) offsets[N_NODES] = base;
}

// ---------------- mlp: 8 edges/wave with M1/M2 register reuse (R9-verified) -
__global__ __launch_bounds__(256) void mlp_kernel(
    const float* __restrict__ esa,   // (E,8)
    const float* __restrict__ M1,    // (8,64)
    const float* __restrict__ M2,    // (64,64)
    const int* __restrict__ edge_dst,
    const int* __restrict__ rank,
    const int* __restrict__ offsets,
    const int* __restrict__ edge_src,
    const float* __restrict__ edge_attr,
    __half* __restrict__ h2csr,      // (E,64) f16, CSR order, pre-scaled 1/8
    int* __restrict__ srcs_csr,
    float* __restrict__ y4csr)
{
    __shared__ __align__(16) float sh[4][8][64];   // 8 KB
    const int wave = threadIdx.x >> 6;
    const int lane = threadIdx.x & 63;
    const int e0 = blockIdx.x * 32 + wave * 8;     // 5000*32 == N_EDGES

    int pos_l = 0;
    if (lane < 8) {
        const int e = e0 + lane;
        pos_l = offsets[edge_dst[e]] + rank[e];
        srcs_csr[pos_l] = edge_src[e];
        ((float4*)y4csr)[pos_l] = ((const float4*)edge_attr)[e];
    }

    const float mye = esa[(size_t)e0 * 8 + lane];

    float m1k[8];
#pragma unroll
    for (int k = 0; k < 8; ++k) m1k[k] = M1[k * 64 + lane];

#pragma unroll
    for (int g = 0; g < 8; ++g) {
        float h = 0.f;
#pragma unroll
        for (int k = 0; k < 8; ++k)
            h += __shfl(mye, g * 8 + k, 64) * m1k[k];   // compile-time lane
        sh[wave][g][lane] = gelu_tanh(h * 0.35355339059327373f);  // 1/sqrt(8)
    }
    __syncthreads();

    float h2[8] = {0,0,0,0,0,0,0,0};
#pragma unroll 4
    for (int q = 0; q < 16; ++q) {
        const float m0 = M2[(4 * q + 0) * 64 + lane];
        const float m1_ = M2[(4 * q + 1) * 64 + lane];
        const float m2_ = M2[(4 * q + 2) * 64 + lane];
        const float m3 = M2[(4 * q + 3) * 64 + lane];
#pragma unroll
        for (int g = 0; g < 8; ++g) {
            const float4 s = *(const float4*)&sh[wave][g][q * 4];
            h2[g] += s.x * m0 + s.y * m1_ + s.z * m2_ + s.w * m3;
        }
    }
#pragma unroll
    for (int g = 0; g < 8; ++g) {
        const float v = gelu_tanh(h2[g] * 0.125f) * 0.125f;  // 1/sqrt(64) x2
        const int pg = __shfl(pos_l, g, 64);
        h2csr[(size_t)pg * 64 + lane] = (__half)v;
    }
}

// ---------------- gather: R12-verified base + self_tbl hoist ONLY -----------
// R13's x8 unroll REVERTED (VGPR 64 + WRITE_SIZE 15.2MB = spill; falsified).
// Single change vs R12: the epilogue self_tbl load is issued in the prologue
// (depends only on node) so its ~600cy L2 round-trip overlaps chunk-0 staging
// instead of extending the block tail. +2 VGPR, mechanism-clear.
__global__ __launch_bounds__(384, 4) void gather_kernel(
    const int* __restrict__ offsets,
    const int* __restrict__ srcs_csr,
    const float* __restrict__ y4csr,
    const __half* __restrict__ h2csr,      // (E,64) f16, CSR order, pre-scaled
    const __half* __restrict__ wtp_pack,   // B-fragment packed Wtp
    const float* __restrict__ feat_tbl,    // (N,320)
    const float* __restrict__ self_tbl,    // (N,320)
    const __half* __restrict__ wo_pack,    // f16 Wo0 (192x128) ++ Wo1 (192x64)
    float* __restrict__ out)               // (N,320)
{
    __shared__ __align__(16) __half wsh[CHUNK * 384];  // 24 KB
    __shared__ __align__(16) char pool[CHUNK * 128];   // 4 KB: h2s ∪ z
    __shared__ float ys[CHUNK][4];
    __shared__ int   srcs[CHUNK];
    __half* h2s = (__half*)pool;
    float*  z   = (float*)pool;                        // 768 floats, fits

    const int node = blockIdx.x;
    const int t = threadIdx.x;             // 0..383
    const int wave = t >> 6, lane = t & 63;
    const int quad = lane >> 4, n16 = lane & 15;

    const int beg = offsets[node], end = offsets[node + 1];

    int cb = beg;
    int ne = min(CHUNK, end - cb);
    half8 hreg = {};
    int   sreg = 0;
    float4 yreg = {0.f, 0.f, 0.f, 0.f};
    if (t < ne * 8) hreg = ((const half8*)(h2csr + (size_t)cb * 64))[t];
    if (t < ne)     { sreg = srcs_csr[cb + t]; yreg = ((const float4*)y4csr)[cb + t]; }

    // ---- hoisted epilogue operand: output column + self value (node-only) --
    int outcol = -1;
    if (t < 128)      outcol = t;
    else if (t < 320) { const int idx = t - 128; outcol = 128 + (idx & 63) * 3 + (idx >> 6); }
    float sv = 0.f;
    if (outcol >= 0) sv = self_tbl[(size_t)node * FEAT_W + outcol];

    half8 bf[4][2];
#pragma unroll
    for (int c = 0; c < 4; ++c) {
        const __half* p = wtp_pack + (size_t)((wave * 4 + c) * 64 + lane) * 16;
        bf[c][0] = *(const half8*)p;
        bf[c][1] = *(const half8*)(p + 8);
    }

    int f0;
    if (t < 128)      f0 = t;
    else if (t < 256) f0 = t - 128;
    else if (t < 320) f0 = 128 + 3 * (t - 256);
    else              f0 = 128 + 3 * (t - 320);

    float acc = 0.f, acc3a = 0.f, acc3b = 0.f, acc3c = 0.f;

    for (;;) {
        if (t < ne) { srcs[t] = sreg; ((float4*)ys)[t] = yreg; }
        if (t < ne * 8) {                              // <=256 units, 1/thread
            const int eL = t >> 3, u = t & 7;
            *(half8*)((char*)h2s + eL * 128 + ((u * 16) ^ ((eL & 7) << 4))) = hreg;
        }
        __syncthreads();

#pragma unroll
        for (int g = 0; g < 2; ++g) {
            if (g * 16 < ne) {                         // rows >= ne never read
                const int e = g * 16 + n16;
                const char* hb = (const char*)h2s + e * 128;
                const int sw = (e & 7) << 4;
                const half8 af0 = *(const half8*)(hb + ((quad * 16) ^ sw));
                const half8 af1 = *(const half8*)(hb + ((64 + quad * 16) ^ sw));
#pragma unroll
                for (int c = 0; c < 4; ++c) {
                    f32x4 acc4 = {0.f, 0.f, 0.f, 0.f};
                    acc4 = __builtin_amdgcn_mfma_f32_16x16x32_f16(af0, bf[c][0], acc4, 0, 0, 0);
                    acc4 = __builtin_amdgcn_mfma_f32_16x16x32_f16(af1, bf[c][1], acc4, 0, 0, 0);
                    const int colb = ((wave * 4 + c) * 16 + n16) * 2;
#pragma unroll
                    for (int r = 0; r < 4; ++r) {
                        const int row = g * 16 + quad * 4 + r;
                        *(__half*)((char*)wsh + row * 768 + (colb ^ (quad << 5))) =
                            (__half)acc4[r];
                    }
                }
            }
        }

        const int cb2 = cb + CHUNK;
        const int ne2 = (cb2 < end) ? min(CHUNK, end - cb2) : 0;
        if (t < ne2 * 8) hreg = ((const half8*)(h2csr + (size_t)cb2 * 64))[t];
        if (t < ne2)     { sreg = srcs_csr[cb2 + t]; yreg = ((const float4*)y4csr)[cb2 + t]; }
        __syncthreads();   // wsh ready

        const int tb = t * 2;
#define WRD(ee) __half2float(*(const __half*)((const char*)wsh + (ee) * 768 + (tb ^ ((((ee) >> 2) & 3) << 5))))
        if (t < 128) {                       // A: mid0a
            int e = 0;
            for (; e + 4 <= ne; e += 4) {
                float w4[4], v4[4]; int s4[4];
#pragma unroll
                for (int k = 0; k < 4; ++k) { w4[k] = WRD(e + k); s4[k] = srcs[e + k]; }
#pragma unroll
                for (int k = 0; k < 4; ++k) v4[k] = feat_tbl[(size_t)s4[k] * FEAT_W + f0];
#pragma unroll
                for (int k = 0; k < 4; ++k) acc += w4[k] * v4[k] * ys[e + k][0];
            }
            for (; e < ne; ++e)
                acc += WRD(e) * feat_tbl[(size_t)srcs[e] * FEAT_W + f0] * ys[e][0];
        } else if (t < 256) {                // B: mid1a
            int e = 0;
            for (; e + 4 <= ne; e += 4) {
                float w4[4], v4[4]; int s4[4];
#pragma unroll
                for (int k = 0; k < 4; ++k) { w4[k] = WRD(e + k); s4[k] = srcs[e + k]; }
#pragma unroll
                for (int k = 0; k < 4; ++k) v4[k] = feat_tbl[(size_t)s4[k] * FEAT_W + f0];
#pragma unroll
                for (int k = 0; k < 4; ++k) {
                    const float p = w4[k] * v4[k];
                    acc3a += p * ys[e + k][1];
                    acc3b += p * ys[e + k][2];
                    acc3c += p * ys[e + k][3];
                }
            }
            for (; e < ne; ++e) {
                const float p = WRD(e) * feat_tbl[(size_t)srcs[e] * FEAT_W + f0];
                acc3a += p * ys[e][1]; acc3b += p * ys[e][2]; acc3c += p * ys[e][3];
            }
        } else if (t < 320) {                // C: mid1b
            int e = 0;
            for (; e + 4 <= ne; e += 4) {
                float w4[4], va[4], vb[4], vc[4]; int s4[4];
#pragma unroll
                for (int k = 0; k < 4; ++k) { w4[k] = WRD(e + k); s4[k] = srcs[e + k]; }
#pragma unroll
                for (int k = 0; k < 4; ++k) {
                    const float* fr = feat_tbl + (size_t)s4[k] * FEAT_W;
                    va[k] = fr[f0]; vb[k] = fr[f0 + 1]; vc[k] = fr[f0 + 2];
                }
#pragma unroll
                for (int k = 0; k < 4; ++k) {
                    const float p = w4[k] * ys[e + k][0];
                    acc3a += p * va[k]; acc3b += p * vb[k]; acc3c += p * vc[k];
                }
            }
            for (; e < ne; ++e) {
                const float* fr = feat_tbl + (size_t)srcs[e] * FEAT_W;
                const float p = WRD(e) * ys[e][0];
                acc3a += p * fr[f0]; acc3b += p * fr[f0 + 1]; acc3c += p * fr[f0 + 2];
            }
        } else {                             // D: mid0b
            int e = 0;
            for (; e + 4 <= ne; e += 4) {
                float w4[4], va[4], vb[4], vc[4]; int s4[4];
#pragma unroll
                for (int k = 0; k < 4; ++k) { w4[k] = WRD(e + k); s4[k] = srcs[e + k]; }
#pragma unroll
                for (int k = 0; k < 4; ++k) {
                    const float* fr = feat_tbl + (size_t)s4[k] * FEAT_W;
                    va[k] = fr[f0]; vb[k] = fr[f0 + 1]; vc[k] = fr[f0 + 2];
                }
#pragma unroll
                for (int k = 0; k < 4; ++k)
                    acc += w4[k] * (va[k] * ys[e + k][1] + vb[k] * ys[e + k][2]
                                  + vc[k] * ys[e + k][3]);
            }
            for (; e < ne; ++e) {
                const float* fr = feat_tbl + (size_t)srcs[e] * FEAT_W;
                acc += WRD(e) * (fr[f0] * ys[e][1] + fr[f0 + 1] * ys[e][2]
                               + fr[f0 + 2] * ys[e][3]);
            }
        }
#undef WRD

        if (!ne2) break;
        cb = cb2; ne = ne2;
        __syncthreads();   // protect wsh/h2s/srcs before overwrite
    }

    // ---- write z (aliases h2s; last h2s read was pre-mid-barrier) ----
    const float sZ = 0.25f;                  // 1/sqrt(16)
    if (t < 128) {
        z[t] = acc * sZ;
    } else if (t < 256) {
        const int u = t - 128;
        z[192 + 0 * 192 + u] = acc3a * sZ;
        z[192 + 1 * 192 + u] = acc3b * sZ;
        z[192 + 2 * 192 + u] = acc3c * sZ;
    } else if (t < 320) {
        const int u = t - 256;
        z[192 + 0 * 192 + 128 + u] = acc3a * sZ;
        z[192 + 1 * 192 + 128 + u] = acc3b * sZ;
        z[192 + 2 * 192 + 128 + u] = acc3c * sZ;
    } else {
        z[128 + (t - 320)] = acc * sZ * 0.5773502691896258f;  // mid0b, 1/sqrt(3)
    }
    __syncthreads();

    // ---- output GEMM (f16 Wo) + rotation combine ----
    const float sA = 0.07216878364870323f;   // 1/sqrt(192)
    const float cR = 0.92387953251128674f;   // cos(pi/8)
    const float sR = 0.38268343236508978f;   // sin(pi/8)
    const __half* Wo0h = wo_pack;            // 192x128
    const __half* Wo1h = wo_pack + 24576;    // 192x64

    if (t < 128) {
        float conv = 0.f;
        const float4* z4 = (const float4*)z;
#pragma unroll 8
        for (int q = 0; q < 48; ++q) {
            const float4 zz = z4[q];
            conv += zz.x * (float)Wo0h[(4 * q + 0) * 128 + t];
            conv += zz.y * (float)Wo0h[(4 * q + 1) * 128 + t];
            conv += zz.z * (float)Wo0h[(4 * q + 2) * 128 + t];
            conv += zz.w * (float)Wo0h[(4 * q + 3) * 128 + t];
        }
        out[(size_t)node * FEAT_W + outcol] = cR * sv + sR * conv * sA;
    } else if (t < 320) {
        const int idx = t - 128;
        const int i = idx >> 6, u = idx & 63;
        float conv = 0.f;
        const float4* z4 = (const float4*)(z + 192 + i * 192);
#pragma unroll 8
        for (int q = 0; q < 48; ++q) {
            const float4 zz = z4[q];
            conv += zz.x * (float)Wo1h[(4 * q + 0) * 64 + u];
            conv += zz.y * (float)Wo1h[(4 * q + 1) * 64 + u];
            conv += zz.z * (float)Wo1h[(4 * q + 2) * 64 + u];
            conv += zz.w * (float)Wo1h[(4 * q + 3) * 64 + u];
        }
        out[(size_t)node * FEAT_W + outcol] = cR * sv + sR * conv * sA;
    }
}

extern "C" void kernel_launch(void* const* d_in, const int* in_sizes, int n_in,
                              void* d_out, int out_size, void* d_ws, size_t ws_size,
                              hipStream_t stream) {
    const float* node_input = (const float*)d_in[0];
    const float* edge_attr  = (const float*)d_in[1];
    const float* esa        = (const float*)d_in[2];
    const float* Wa0  = (const float*)d_in[3];
    const float* Wa1  = (const float*)d_in[4];
    const float* Wb0  = (const float*)d_in[5];
    const float* Wb1  = (const float*)d_in[6];
    const float* M1   = (const float*)d_in[7];
    const float* M2   = (const float*)d_in[8];
    const float* Wtp0 = (const float*)d_in[9];
    const float* Wtp1 = (const float*)d_in[10];
    const float* Wtp2 = (const float*)d_in[11];
    const float* Wtp3 = (const float*)d_in[12];
    const float* Wo0  = (const float*)d_in[13];
    const float* Wo1  = (const float*)d_in[14];
    const int* edge_src = (const int*)d_in[15];
    const int* edge_dst = (const int*)d_in[16];
    float* out = (float*)d_out;

    // ws layout (~46 MB), 16B-aligned segments
    char* w = (char*)d_ws;
    float*  feat_tbl = (float*)w;           w += (size_t)N_NODES * FEAT_W * 4;
    float*  self_tbl = (float*)w;           w += (size_t)N_NODES * FEAT_W * 4;
    float*  y4csr    = (float*)w;           w += (size_t)N_EDGES * 4 * 4;
    __half* h2csr    = (__half*)w;          w += (size_t)N_EDGES * 64 * 2;
    __half* wtp_pack = (__half*)w;          w += (size_t)24576 * 2;
    __half* wo_pack  = (__half*)w;          w += (size_t)36864 * 2;
    int*    counts   = (int*)w;             w += (size_t)N_NODES * 4;
    int*    offsets  = (int*)w;             w += (size_t)(N_NODES + 1) * 4;
    int*    rank     = (int*)w;             w += (size_t)N_EDGES * 4;
    int*    srcs_csr = (int*)w;             w += (size_t)N_EDGES * 4;

    hipMemsetAsync(counts, 0, sizeof(int) * N_NODES, stream);

    prep_kernel<<<1870, 320, 0, stream>>>(node_input, Wa0, Wa1, Wb0, Wb1,
                                          feat_tbl, self_tbl,
                                          edge_dst, counts, rank,
                                          Wtp0, Wtp1, Wtp2, Wtp3, Wo0, Wo1,
                                          wtp_pack, wo_pack);
    scan_kernel<<<1, 1024, 0, stream>>>(counts, offsets);
    mlp_kernel<<<N_EDGES / 32, 256, 0, stream>>>(esa, M1, M2, edge_dst, rank, offsets,
                                                 edge_src, edge_attr,
                                                 h2csr, srcs_csr, y4csr);
    gather_kernel<<<N_NODES, 384, 0, stream>>>(offsets, srcs_csr, y4csr, h2csr,
                                               wtp_pack, feat_tbl, self_tbl,
                                               wo_pack, out);
}

// Round 15
// 329.955 us; speedup vs baseline: 1.0717x; 1.0717x over previous
//
#include <hip/hip_runtime.h>
#include <hip/hip_bf16.h>
#include <hip/hip_fp16.h>

#define N_NODES 10000
#define N_EDGES 160000
#define FEAT_W 320
#define CHUNK 32

typedef _Float16 half8 __attribute__((ext_vector_type(8)));
typedef float f32x4 __attribute__((ext_vector_type(4)));

// fast gelu: tanh(y) = 1 - 2/(exp(2y)+1)  (no NaN at +/-inf, ~1e-7 abs err)
__device__ __forceinline__ float gelu_tanh(float x) {
    float x3 = x * x * x;
    float y = 0.7978845608028654f * (x + 0.044715f * x3);
    float th = 1.f - 2.f / (__expf(2.f * y) + 1.f);
    return 0.5f * x * (1.f + th);
}

// ---------------- prep: node transforms ∥ degree count+rank ∥ weight pack ---
// (R6/R7/R9/R12-verified)
__global__ __launch_bounds__(320) void prep_kernel(
    const float* __restrict__ node_input,
    const float* __restrict__ Wa0, const float* __restrict__ Wa1,
    const float* __restrict__ Wb0, const float* __restrict__ Wb1,
    float* __restrict__ feat_tbl, float* __restrict__ self_tbl,
    const int* __restrict__ edge_dst, int* __restrict__ counts,
    int* __restrict__ rank,
    const float* __restrict__ Wtp0, const float* __restrict__ Wtp1,
    const float* __restrict__ Wtp2, const float* __restrict__ Wtp3,
    const float* __restrict__ Wo0,  const float* __restrict__ Wo1,
    __half* __restrict__ wtp_pack, __half* __restrict__ wo_pack)
{
    __shared__ __align__(16) float xT[FEAT_W][8];   // 10.24 KB (NT branch only)
    const int t = threadIdx.x;

    if (blockIdx.x < 1250) {
        const int node0 = blockIdx.x * 8;
        for (int q = t; q < 640; q += 320) {            // 8 rows x 80 float4
            const int n = q / 80, c4 = q - n * 80;
            const float4 v = ((const float4*)(node_input + (size_t)(node0 + n) * FEAT_W))[c4];
            xT[c4 * 4 + 0][n] = v.x; xT[c4 * 4 + 1][n] = v.y;
            xT[c4 * 4 + 2][n] = v.z; xT[c4 * 4 + 3][n] = v.w;
        }
        __syncthreads();

        float accf[8] = {0,0,0,0,0,0,0,0}, accs[8] = {0,0,0,0,0,0,0,0};
        float scale;
        if (t < 128) {
            for (int v = 0; v < 128; ++v) {
                const float wa = Wa0[v * 128 + t];
                const float wb = Wb0[v * 128 + t];
                const float4 xa = *(const float4*)&xT[v][0];
                const float4 xb = *(const float4*)&xT[v][4];
                accf[0] += xa.x * wa; accf[1] += xa.y * wa; accf[2] += xa.z * wa; accf[3] += xa.w * wa;
                accf[4] += xb.x * wa; accf[5] += xb.y * wa; accf[6] += xb.z * wa; accf[7] += xb.w * wa;
                accs[0] += xa.x * wb; accs[1] += xa.y * wb; accs[2] += xa.z * wb; accs[3] += xa.w * wb;
                accs[4] += xb.x * wb; accs[5] += xb.y * wb; accs[6] += xb.z * wb; accs[7] += xb.w * wb;
            }
            scale = 0.08838834764831845f;               // 1/sqrt(128)
        } else {
            const int r = t - 128, u = r / 3, i = r - 3 * u;
            for (int v = 0; v < 64; ++v) {
                const float wa = Wa1[v * 64 + u];
                const float wb = Wb1[v * 64 + u];
                const int row = 128 + v * 3 + i;
                const float4 xa = *(const float4*)&xT[row][0];
                const float4 xb = *(const float4*)&xT[row][4];
                accf[0] += xa.x * wa; accf[1] += xa.y * wa; accf[2] += xa.z * wa; accf[3] += xa.w * wa;
                accf[4] += xb.x * wa; accf[5] += xb.y * wa; accf[6] += xb.z * wa; accf[7] += xb.w * wa;
                accs[0] += xa.x * wb; accs[1] += xa.y * wb; accs[2] += xa.z * wb; accs[3] += xa.w * wb;
                accs[4] += xb.x * wb; accs[5] += xb.y * wb; accs[6] += xb.z * wb; accs[7] += xb.w * wb;
            }
            scale = 0.125f;                             // 1/sqrt(64)
        }
#pragma unroll
        for (int n = 0; n < 8; ++n) {
            feat_tbl[(size_t)(node0 + n) * FEAT_W + t] = accf[n] * scale;
            self_tbl[(size_t)(node0 + n) * FEAT_W + t] = accs[n] * scale;
        }
    } else if (blockIdx.x < 1750) {
        const int e = (blockIdx.x - 1250) * 320 + t;    // 500*320 == N_EDGES
        rank[e] = atomicAdd(&counts[edge_dst[e]], 1);
    } else {
        const int gid = (blockIdx.x - 1750) * 320 + t;  // 120*320 = 38400
        if (gid < 1536) {                               // 24 tiles * 64 lanes
            const int lane = gid & 63;
            const int tile = gid >> 6;
            const int quad = lane >> 4, n16 = lane & 15;
            const int col = tile * 16 + n16;
            const float* src; int stride;
            if (col < 128)      { src = Wtp0 + col;         stride = 128; }
            else if (col < 256) { src = Wtp1 + (col - 128); stride = 128; }
            else if (col < 320) { src = Wtp2 + (col - 256); stride = 64;  }
            else                { src = Wtp3 + (col - 320); stride = 64;  }
            __half* dst = wtp_pack + (size_t)gid * 16;
#pragma unroll
            for (int s = 0; s < 2; ++s)
#pragma unroll
                for (int j = 0; j < 8; ++j)
                    dst[s * 8 + j] = (__half)src[(s * 32 + quad * 8 + j) * stride];
        } else if (gid < 38400) {
            const int i = gid - 1536;                   // 36864 = 192*128 + 192*64
            if (i < 24576) wo_pack[i] = (__half)Wo0[i];
            else           wo_pack[i] = (__half)Wo1[i - 24576];
        }
    }
}

// ---------------- CSR scan --------------------------------------------------
__global__ __launch_bounds__(1024) void scan_kernel(
    const int* __restrict__ counts, int* __restrict__ offsets)
{
    __shared__ int wsum[16];
    const int wid = threadIdx.x >> 6, lane = threadIdx.x & 63;
    int base = 0;
    for (int c = 0; c < 10; ++c) {            // 10*1024 >= 10000
        const int i = c * 1024 + threadIdx.x;
        const int v = (i < N_NODES) ? counts[i] : 0;
        int x = v;
#pragma unroll
        for (int off = 1; off < 64; off <<= 1) {
            int y = __shfl_up(x, off, 64);
            if (lane >= off) x += y;
        }
        if (lane == 63) wsum[wid] = x;
        __syncthreads();
        if (threadIdx.x < 16) {
            int s = wsum[threadIdx.x];
#pragma unroll
            for (int off = 1; off < 16; off <<= 1) {
                int y = __shfl_up(s, off, 64);
                if ((int)threadIdx.x >= off) s += y;
            }
            wsum[threadIdx.x] = s;
        }
        __syncthreads();
        const int waveoff = (wid == 0) ? 0 : wsum[wid - 1];
        const int excl = base + waveoff + x - v;
        if (i < N_NODES) offsets[i] = excl;
        const int tot = wsum[15];
        __syncthreads();
        base += tot;
    }
    if (threadIdx.x == 0) offsets[N_NODES] = base;
}

// ---------------- mlp: 8 edges/wave with M1/M2 register reuse (R9-verified) -
__global__ __launch_bounds__(256) void mlp_kernel(
    const float* __restrict__ esa,   // (E,8)
    const float* __restrict__ M1,    // (8,64)
    const float* __restrict__ M2,    // (64,64)
    const int* __restrict__ edge_dst,
    const int* __restrict__ rank,
    const int* __restrict__ offsets,
    const int* __restrict__ edge_src,
    const float* __restrict__ edge_attr,
    __half* __restrict__ h2csr,      // (E,64) f16, CSR order, pre-scaled 1/8
    int* __restrict__ srcs_csr,
    float* __restrict__ y4csr)
{
    __shared__ __align__(16) float sh[4][8][64];   // 8 KB
    const int wave = threadIdx.x >> 6;
    const int lane = threadIdx.x & 63;
    const int e0 = blockIdx.x * 32 + wave * 8;     // 5000*32 == N_EDGES

    int pos_l = 0;
    if (lane < 8) {
        const int e = e0 + lane;
        pos_l = offsets[edge_dst[e]] + rank[e];
        srcs_csr[pos_l] = edge_src[e];
        ((float4*)y4csr)[pos_l] = ((const float4*)edge_attr)[e];
    }

    const float mye = esa[(size_t)e0 * 8 + lane];

    float m1k[8];
#pragma unroll
    for (int k = 0; k < 8; ++k) m1k[k] = M1[k * 64 + lane];

#pragma unroll
    for (int g = 0; g < 8; ++g) {
        float h = 0.f;
#pragma unroll
        for (int k = 0; k < 8; ++k)
            h += __shfl(mye, g * 8 + k, 64) * m1k[k];   // compile-time lane
        sh[wave][g][lane] = gelu_tanh(h * 0.35355339059327373f);  // 1/sqrt(8)
    }
    __syncthreads();

    float h2[8] = {0,0,0,0,0,0,0,0};
#pragma unroll 4
    for (int q = 0; q < 16; ++q) {
        const float m0 = M2[(4 * q + 0) * 64 + lane];
        const float m1_ = M2[(4 * q + 1) * 64 + lane];
        const float m2_ = M2[(4 * q + 2) * 64 + lane];
        const float m3 = M2[(4 * q + 3) * 64 + lane];
#pragma unroll
        for (int g = 0; g < 8; ++g) {
            const float4 s = *(const float4*)&sh[wave][g][q * 4];
            h2[g] += s.x * m0 + s.y * m1_ + s.z * m2_ + s.w * m3;
        }
    }
#pragma unroll
    for (int g = 0; g < 8; ++g) {
        const float v = gelu_tanh(h2[g] * 0.125f) * 0.125f;  // 1/sqrt(64) x2
        const int pg = __shfl(pos_l, g, 64);
        h2csr[(size_t)pg * 64 + lane] = (__half)v;
    }
}

// ---------------- gather: R5/R9/R12-verified (161-162 us) -------------------
// Falsified variants (all regressed): persistence (R6), merged roles (R7),
// in-register MFMA consumption (R8), feat-LDS staging (R10), elist
// indirection (R11), x8 unroll (R13, spill), self_tbl hoist (R14).
__global__ __launch_bounds__(384, 4) void gather_kernel(
    const int* __restrict__ offsets,
    const int* __restrict__ srcs_csr,
    const float* __restrict__ y4csr,
    const __half* __restrict__ h2csr,      // (E,64) f16, CSR order, pre-scaled
    const __half* __restrict__ wtp_pack,   // B-fragment packed Wtp
    const float* __restrict__ feat_tbl,    // (N,320)
    const float* __restrict__ self_tbl,    // (N,320)
    const __half* __restrict__ wo_pack,    // f16 Wo0 (192x128) ++ Wo1 (192x64)
    float* __restrict__ out)               // (N,320)
{
    __shared__ __align__(16) __half wsh[CHUNK * 384];  // 24 KB
    __shared__ __align__(16) char pool[CHUNK * 128];   // 4 KB: h2s ∪ z
    __shared__ float ys[CHUNK][4];
    __shared__ int   srcs[CHUNK];
    __half* h2s = (__half*)pool;
    float*  z   = (float*)pool;                        // 768 floats, fits

    const int node = blockIdx.x;
    const int t = threadIdx.x;             // 0..383
    const int wave = t >> 6, lane = t & 63;
    const int quad = lane >> 4, n16 = lane & 15;

    const int beg = offsets[node], end = offsets[node + 1];

    int cb = beg;
    int ne = min(CHUNK, end - cb);
    half8 hreg = {};
    int   sreg = 0;
    float4 yreg = {0.f, 0.f, 0.f, 0.f};
    if (t < ne * 8) hreg = ((const half8*)(h2csr + (size_t)cb * 64))[t];
    if (t < ne)     { sreg = srcs_csr[cb + t]; yreg = ((const float4*)y4csr)[cb + t]; }

    half8 bf[4][2];
#pragma unroll
    for (int c = 0; c < 4; ++c) {
        const __half* p = wtp_pack + (size_t)((wave * 4 + c) * 64 + lane) * 16;
        bf[c][0] = *(const half8*)p;
        bf[c][1] = *(const half8*)(p + 8);
    }

    int f0;
    if (t < 128)      f0 = t;
    else if (t < 256) f0 = t - 128;
    else if (t < 320) f0 = 128 + 3 * (t - 256);
    else              f0 = 128 + 3 * (t - 320);

    float acc = 0.f, acc3a = 0.f, acc3b = 0.f, acc3c = 0.f;

    for (;;) {
        if (t < ne) { srcs[t] = sreg; ((float4*)ys)[t] = yreg; }
        if (t < ne * 8) {                              // <=256 units, 1/thread
            const int eL = t >> 3, u = t & 7;
            *(half8*)((char*)h2s + eL * 128 + ((u * 16) ^ ((eL & 7) << 4))) = hreg;
        }
        __syncthreads();

#pragma unroll
        for (int g = 0; g < 2; ++g) {
            if (g * 16 < ne) {                         // rows >= ne never read
                const int e = g * 16 + n16;
                const char* hb = (const char*)h2s + e * 128;
                const int sw = (e & 7) << 4;
                const half8 af0 = *(const half8*)(hb + ((quad * 16) ^ sw));
                const half8 af1 = *(const half8*)(hb + ((64 + quad * 16) ^ sw));
#pragma unroll
                for (int c = 0; c < 4; ++c) {
                    f32x4 acc4 = {0.f, 0.f, 0.f, 0.f};
                    acc4 = __builtin_amdgcn_mfma_f32_16x16x32_f16(af0, bf[c][0], acc4, 0, 0, 0);
                    acc4 = __builtin_amdgcn_mfma_f32_16x16x32_f16(af1, bf[c][1], acc4, 0, 0, 0);
                    const int colb = ((wave * 4 + c) * 16 + n16) * 2;
#pragma unroll
                    for (int r = 0; r < 4; ++r) {
                        const int row = g * 16 + quad * 4 + r;
                        *(__half*)((char*)wsh + row * 768 + (colb ^ (quad << 5))) =
                            (__half)acc4[r];
                    }
                }
            }
        }

        const int cb2 = cb + CHUNK;
        const int ne2 = (cb2 < end) ? min(CHUNK, end - cb2) : 0;
        if (t < ne2 * 8) hreg = ((const half8*)(h2csr + (size_t)cb2 * 64))[t];
        if (t < ne2)     { sreg = srcs_csr[cb2 + t]; yreg = ((const float4*)y4csr)[cb2 + t]; }
        __syncthreads();   // wsh ready

        const int tb = t * 2;
#define WRD(ee) __half2float(*(const __half*)((const char*)wsh + (ee) * 768 + (tb ^ ((((ee) >> 2) & 3) << 5))))
        if (t < 128) {                       // A: mid0a
            int e = 0;
            for (; e + 4 <= ne; e += 4) {
                float w4[4], v4[4]; int s4[4];
#pragma unroll
                for (int k = 0; k < 4; ++k) { w4[k] = WRD(e + k); s4[k] = srcs[e + k]; }
#pragma unroll
                for (int k = 0; k < 4; ++k) v4[k] = feat_tbl[(size_t)s4[k] * FEAT_W + f0];
#pragma unroll
                for (int k = 0; k < 4; ++k) acc += w4[k] * v4[k] * ys[e + k][0];
            }
            for (; e < ne; ++e)
                acc += WRD(e) * feat_tbl[(size_t)srcs[e] * FEAT_W + f0] * ys[e][0];
        } else if (t < 256) {                // B: mid1a
            int e = 0;
            for (; e + 4 <= ne; e += 4) {
                float w4[4], v4[4]; int s4[4];
#pragma unroll
                for (int k = 0; k < 4; ++k) { w4[k] = WRD(e + k); s4[k] = srcs[e + k]; }
#pragma unroll
                for (int k = 0; k < 4; ++k) v4[k] = feat_tbl[(size_t)s4[k] * FEAT_W + f0];
#pragma unroll
                for (int k = 0; k < 4; ++k) {
                    const float p = w4[k] * v4[k];
                    acc3a += p * ys[e + k][1];
                    acc3b += p * ys[e + k][2];
                    acc3c += p * ys[e + k][3];
                }
            }
            for (; e < ne; ++e) {
                const float p = WRD(e) * feat_tbl[(size_t)srcs[e] * FEAT_W + f0];
                acc3a += p * ys[e][1]; acc3b += p * ys[e][2]; acc3c += p * ys[e][3];
            }
        } else if (t < 320) {                // C: mid1b
            int e = 0;
            for (; e + 4 <= ne; e += 4) {
                float w4[4], va[4], vb[4], vc[4]; int s4[4];
#pragma unroll
                for (int k = 0; k < 4; ++k) { w4[k] = WRD(e + k); s4[k] = srcs[e + k]; }
#pragma unroll
                for (int k = 0; k < 4; ++k) {
                    const float* fr = feat_tbl + (size_t)s4[k] * FEAT_W;
                    va[k] = fr[f0]; vb[k] = fr[f0 + 1]; vc[k] = fr[f0 + 2];
                }
#pragma unroll
                for (int k = 0; k < 4; ++k) {
                    const float p = w4[k] * ys[e + k][0];
                    acc3a += p * va[k]; acc3b += p * vb[k]; acc3c += p * vc[k];
                }
            }
            for (; e < ne; ++e) {
                const float* fr = feat_tbl + (size_t)srcs[e] * FEAT_W;
                const float p = WRD(e) * ys[e][0];
                acc3a += p * fr[f0]; acc3b += p * fr[f0 + 1]; acc3c += p * fr[f0 + 2];
            }
        } else {                             // D: mid0b
            int e = 0;
            for (; e + 4 <= ne; e += 4) {
                float w4[4], va[4], vb[4], vc[4]; int s4[4];
#pragma unroll
                for (int k = 0; k < 4; ++k) { w4[k] = WRD(e + k); s4[k] = srcs[e + k]; }
#pragma unroll
                for (int k = 0; k < 4; ++k) {
                    const float* fr = feat_tbl + (size_t)s4[k] * FEAT_W;
                    va[k] = fr[f0]; vb[k] = fr[f0 + 1]; vc[k] = fr[f0 + 2];
                }
#pragma unroll
                for (int k = 0; k < 4; ++k)
                    acc += w4[k] * (va[k] * ys[e + k][1] + vb[k] * ys[e + k][2]
                                  + vc[k] * ys[e + k][3]);
            }
            for (; e < ne; ++e) {
                const float* fr = feat_tbl + (size_t)srcs[e] * FEAT_W;
                acc += WRD(e) * (fr[f0] * ys[e][1] + fr[f0 + 1] * ys[e][2]
                               + fr[f0 + 2] * ys[e][3]);
            }
        }
#undef WRD

        if (!ne2) break;
        cb = cb2; ne = ne2;
        __syncthreads();   // protect wsh/h2s/srcs before overwrite
    }

    // ---- write z (aliases h2s; last h2s read was pre-mid-barrier) ----
    const float sZ = 0.25f;                  // 1/sqrt(16)
    if (t < 128) {
        z[t] = acc * sZ;
    } else if (t < 256) {
        const int u = t - 128;
        z[192 + 0 * 192 + u] = acc3a * sZ;
        z[192 + 1 * 192 + u] = acc3b * sZ;
        z[192 + 2 * 192 + u] = acc3c * sZ;
    } else if (t < 320) {
        const int u = t - 256;
        z[192 + 0 * 192 + 128 + u] = acc3a * sZ;
        z[192 + 1 * 192 + 128 + u] = acc3b * sZ;
        z[192 + 2 * 192 + 128 + u] = acc3c * sZ;
    } else {
        z[128 + (t - 320)] = acc * sZ * 0.5773502691896258f;  // mid0b, 1/sqrt(3)
    }
    __syncthreads();

    // ---- output GEMM (f16 Wo) + rotation combine ----
    const float sA = 0.07216878364870323f;   // 1/sqrt(192)
    const float cR = 0.92387953251128674f;   // cos(pi/8)
    const float sR = 0.38268343236508978f;   // sin(pi/8)
    const __half* Wo0h = wo_pack;            // 192x128
    const __half* Wo1h = wo_pack + 24576;    // 192x64

    if (t < 128) {
        float conv = 0.f;
        const float4* z4 = (const float4*)z;
#pragma unroll 8
        for (int q = 0; q < 48; ++q) {
            const float4 zz = z4[q];
            conv += zz.x * (float)Wo0h[(4 * q + 0) * 128 + t];
            conv += zz.y * (float)Wo0h[(4 * q + 1) * 128 + t];
            conv += zz.z * (float)Wo0h[(4 * q + 2) * 128 + t];
            conv += zz.w * (float)Wo0h[(4 * q + 3) * 128 + t];
        }
        const float sv = self_tbl[(size_t)node * FEAT_W + t];
        out[(size_t)node * FEAT_W + t] = cR * sv + sR * conv * sA;
    } else if (t < 320) {
        const int idx = t - 128;
        const int i = idx >> 6, u = idx & 63;
        float conv = 0.f;
        const float4* z4 = (const float4*)(z + 192 + i * 192);
#pragma unroll 8
        for (int q = 0; q < 48; ++q) {
            const float4 zz = z4[q];
            conv += zz.x * (float)Wo1h[(4 * q + 0) * 64 + u];
            conv += zz.y * (float)Wo1h[(4 * q + 1) * 64 + u];
            conv += zz.z * (float)Wo1h[(4 * q + 2) * 64 + u];
            conv += zz.w * (float)Wo1h[(4 * q + 3) * 64 + u];
        }
        const int col = 128 + u * 3 + i;
        const float sv = self_tbl[(size_t)node * FEAT_W + col];
        out[(size_t)node * FEAT_W + col] = cR * sv + sR * conv * sA;
    }
}

extern "C" void kernel_launch(void* const* d_in, const int* in_sizes, int n_in,
                              void* d_out, int out_size, void* d_ws, size_t ws_size,
                              hipStream_t stream) {
    const float* node_input = (const float*)d_in[0];
    const float* edge_attr  = (const float*)d_in[1];
    const float* esa        = (const float*)d_in[2];
    const float* Wa0  = (const float*)d_in[3];
    const float* Wa1  = (const float*)d_in[4];
    const float* Wb0  = (const float*)d_in[5];
    const float* Wb1  = (const float*)d_in[6];
    const float* M1   = (const float*)d_in[7];
    const float* M2   = (const float*)d_in[8];
    const float* Wtp0 = (const float*)d_in[9];
    const float* Wtp1 = (const float*)d_in[10];
    const float* Wtp2 = (const float*)d_in[11];
    const float* Wtp3 = (const float*)d_in[12];
    const float* Wo0  = (const float*)d_in[13];
    const float* Wo1  = (const float*)d_in[14];
    const int* edge_src = (const int*)d_in[15];
    const int* edge_dst = (const int*)d_in[16];
    float* out = (float*)d_out;

    // ws layout (~46 MB), 16B-aligned segments
    char* w = (char*)d_ws;
    float*  feat_tbl = (float*)w;           w += (size_t)N_NODES * FEAT_W * 4;
    float*  self_tbl = (float*)w;           w += (size_t)N_NODES * FEAT_W * 4;
    float*  y4csr    = (float*)w;           w += (size_t)N_EDGES * 4 * 4;
    __half* h2csr    = (__half*)w;          w += (size_t)N_EDGES * 64 * 2;
    __half* wtp_pack = (__half*)w;          w += (size_t)24576 * 2;
    __half* wo_pack  = (__half*)w;          w += (size_t)36864 * 2;
    int*    counts   = (int*)w;             w += (size_t)N_NODES * 4;
    int*    offsets  = (int*)w;             w += (size_t)(N_NODES + 1) * 4;
    int*    rank     = (int*)w;             w += (size_t)N_EDGES * 4;
    int*    srcs_csr = (int*)w;             w += (size_t)N_EDGES * 4;

    hipMemsetAsync(counts, 0, sizeof(int) * N_NODES, stream);

    prep_kernel<<<1870, 320, 0, stream>>>(node_input, Wa0, Wa1, Wb0, Wb1,
                                          feat_tbl, self_tbl,
                                          edge_dst, counts, rank,
                                          Wtp0, Wtp1, Wtp2, Wtp3, Wo0, Wo1,
                                          wtp_pack, wo_pack);
    scan_kernel<<<1, 1024, 0, stream>>>(counts, offsets);
    mlp_kernel<<<N_EDGES / 32, 256, 0, stream>>>(esa, M1, M2, edge_dst, rank, offsets,
                                                 edge_src, edge_attr,
                                                 h2csr, srcs_csr, y4csr);
    gather_kernel<<<N_NODES, 384, 0, stream>>>(offsets, srcs_csr, y4csr, h2csr,
                                               wtp_pack, feat_tbl, self_tbl,
                                               wo_pack, out);
}